// Round 10
// baseline (209.844 us; speedup 1.0000x reference)
//
#include <hip/hip_runtime.h>

#define HW 16384      // 128*128
#define BS 8
#define NC 256        // feature channels
#define K  19         // classes
#define Q  2975
#define INV_T 5.0f    // 1/0.2
#define NCHUNK 4
#define QC 744        // 4*744 = 2976 >= 2975
#define NB1 512       // k1 grid: NB1*256 == BS*HW == 131072 exactly (1 pixel/thread)

// ---------------- K1: argmax + copy res->out + per-block histogram ----------------
// scalar float per thread, 512 blocks; block0 zeroes sums; nontemporal out stores
__global__ void __launch_bounds__(256) k1_argmax(const float* __restrict__ res,
                                                 float* __restrict__ out,
                                                 unsigned char* __restrict__ pred,
                                                 int* __restrict__ histb,
                                                 float* __restrict__ sums) {
    __shared__ int hist[K];
    int t = threadIdx.x;
    if (t < K) hist[t] = 0;
    __syncthreads();
    int gp = blockIdx.x * 256 + t;          // 0 .. BS*HW-1, exact cover
    int b  = gp >> 14;
    int p  = gp & (HW - 1);
    const float* rb = res + (size_t)b * K * HW + p;
    float*       ob = out + (size_t)b * K * HW + p;
    float best = rb[0];
    int   bk   = 0;
    __builtin_nontemporal_store(best, &ob[0]);
    #pragma unroll
    for (int k = 1; k < K; ++k) {
        float v = rb[(size_t)k * HW];
        __builtin_nontemporal_store(v, &ob[(size_t)k * HW]);
        if (v > best) { best = v; bk = k; }   // strict > keeps first index
    }
    pred[gp] = (unsigned char)bk;
    atomicAdd(&hist[bk], 1);
    if (blockIdx.x == 0) {                    // zero sums for k2
        for (int i = t; i < K * NC; i += 256) sums[i] = 0.f;
    }
    __syncthreads();
    if (t < K) histb[t * NB1 + blockIdx.x] = hist[t];   // k-major, no global atomics
}

// ---------------- K2: per-class pooling: sums[k][c] = sum of fea over pred==k ----------------
// one block per (b,c) row; per-thread LDS column accumulators.
// atomicAdd on LDS -> ds_add_f32 (no return): kills the read-modify-write dependency
// chain the compiler otherwise serializes (it can't prove kk.x..kk.w don't alias).
// Each thread owns column t exclusively -> zero contention; bank = t%32, 2-way = free.
__global__ void __launch_bounds__(256) k2_pool(const float* __restrict__ fea,
                                               const unsigned char* __restrict__ pred,
                                               float* __restrict__ sums) {
    __shared__ float acc[K * 256];
    int t = threadIdx.x, lane = t & 63, w = t >> 6;
    int b = blockIdx.x >> 8;
    int c = blockIdx.x & 255;
    #pragma unroll
    for (int k = 0; k < K; ++k) acc[k * 256 + t] = 0.f;
    __syncthreads();
    const float4* f4 = (const float4*)(fea + (size_t)(b * NC + c) * HW);
    const uchar4* p4 = (const uchar4*)(pred + (size_t)b * HW);
    #pragma unroll 2
    for (int i = t; i < HW / 4; i += 256) {
        float4 v  = f4[i];
        uchar4 kk = p4[i];
        atomicAdd(&acc[kk.x * 256 + t], v.x);
        atomicAdd(&acc[kk.y * 256 + t], v.y);
        atomicAdd(&acc[kk.z * 256 + t], v.z);
        atomicAdd(&acc[kk.w * 256 + t], v.w);
    }
    __syncthreads();
    // wave w reduces classes k = w, w+4, ... : 4 LDS reads + shuffle tree + 1 atomic
    for (int k = w; k < K; k += 4) {
        float v = acc[k * 256 + lane]       + acc[k * 256 + lane + 64]
                + acc[k * 256 + lane + 128] + acc[k * 256 + lane + 192];
        #pragma unroll
        for (int off = 32; off > 0; off >>= 1) v += __shfl_xor(v, off, 64);
        if (lane == 0) atomicAdd(&sums[k * NC + c], v);
    }
}

// ---------------- K4: inline norms + partial sum-of-exp over a q-chunk (fixed max = 0) ----
// grid (NC, NCHUNK); block 256.
// keys = sums / max(||sums||, 1e-12)  (cnt term in the reference eps can only matter if
// 1e-12 <= ||sums|| < cnt*1e-12 <= 1.3e-7 — impossible: present classes have O(1) norms,
// absent classes are exactly 0 and give key = 0 either way)
__global__ void __launch_bounds__(256, 4) k4_lse(const float* __restrict__ queues,
                                                 const float* __restrict__ sums,
                                                 float* __restrict__ spart,
                                                 float* __restrict__ pos0) {
    int t = threadIdx.x;
    int c = blockIdx.x;
    int chunk = blockIdx.y;
    int lane = t & 63, wv = t >> 6;

    // --- phase A: per-class INV_T/||sums|| (wave wv handles k = wv, wv+4, ...) ---
    __shared__ float sc_sh[K];
    for (int k = wv; k < K; k += 4) {
        float ss = 0.f;
        #pragma unroll
        for (int j = 0; j < 4; ++j) {
            float v = sums[k * NC + j * 64 + lane];
            ss += v * v;
        }
        #pragma unroll
        for (int off = 32; off > 0; off >>= 1) ss += __shfl_xor(ss, off, 64);
        if (lane == 0) sc_sh[k] = INV_T / fmaxf(sqrtf(ss), 1e-12f);
    }
    __syncthreads();

    float key[K], s[K];
    #pragma unroll
    for (int k = 0; k < K; ++k) {
        key[k] = sums[k * NC + c] * sc_sh[k];   // uniform addr -> broadcast load
        s[k] = 0.f;
    }
    if (chunk == 0 && t < K)
        pos0[t * NC + c] = sums[t * NC + c] * sc_sh[t] * queues[(size_t)(t * NC + c) * Q];

    int q0 = chunk * QC;
    int qhi = min(Q, q0 + QC);
    for (int q = q0 + t; q < qhi; q += 256) {
        float qv[K];
        float qs = 0.f;
        #pragma unroll
        for (int k = 0; k < K; ++k) {
            qv[k] = queues[(size_t)(k * NC + c) * Q + q];
            qs += qv[k];
        }
        #pragma unroll
        for (int k = 0; k < K; ++k) {
            float a  = key[k] * qv[k];                // l_pos/T
            float bn = fmaf(key[k], qs, -a);          // l_neg/T
            s[k] += __expf(a) + __expf(bn);
        }
    }

    // reduce s[k] across the block: per-wave shuffles, then cross-wave via LDS
    __shared__ float sw[K][4];
    #pragma unroll
    for (int k = 0; k < K; ++k) {
        float sk = s[k];
        #pragma unroll
        for (int off = 32; off > 0; off >>= 1) sk += __shfl_xor(sk, off, 64);
        if (lane == 0) sw[k][wv] = sk;
    }
    __syncthreads();
    if (t < K)
        spart[((size_t)t * NC + c) * NCHUNK + chunk] = sw[t][0] + sw[t][1] + sw[t][2] + sw[t][3];
}

// ---------------- K5: counts from histb + merge chunks + loss ----------------
__global__ void k5_final(const float* __restrict__ spart, const float* __restrict__ pos0,
                         const int* __restrict__ histb, float* __restrict__ loss) {
    __shared__ float cnt_sh[K];
    int t = threadIdx.x, lane = t & 63, w = t >> 6;
    for (int k = w; k < K; k += 4) {
        float cf = 0.f;
        #pragma unroll
        for (int j = 0; j < NB1 / 64; ++j)
            cf += (float)histb[k * NB1 + j * 64 + lane];
        #pragma unroll
        for (int off = 32; off > 0; off >>= 1) cf += __shfl_xor(cf, off, 64);
        if (lane == 0) cnt_sh[k] = cf;
    }
    __syncthreads();
    float acc = 0.f;   // thread t plays channel c = t
    #pragma unroll
    for (int k = 0; k < K; ++k) {
        float4 sp = ((const float4*)spart)[k * NC + t];
        float lse = logf(sp.x + sp.y + sp.z + sp.w);
        if (cnt_sh[k] > 0.5f) acc += lse - pos0[k * NC + t];
    }
    __shared__ float red[256];
    red[t] = acc;
    __syncthreads();
    for (int s = 128; s > 0; s >>= 1) {
        if (t < s) red[t] += red[t + s];
        __syncthreads();
    }
    if (t == 0) *loss = red[0] * (1.0f / 256.0f);
}

extern "C" void kernel_launch(void* const* d_in, const int* in_sizes, int n_in,
                              void* d_out, int out_size, void* d_ws, size_t ws_size,
                              hipStream_t stream) {
    const float* fea    = (const float*)d_in[0];   // [8,256,128,128]
    const float* res    = (const float*)d_in[1];   // [8,19,128,128]
    const float* queues = (const float*)d_in[2];   // [19,256,2975]

    float* out  = (float*)d_out;                   // res copy, then loss scalar
    float* loss = out + (size_t)BS * K * HW;       // element 2490368

    char* ws = (char*)d_ws;
    float*         sums   = (float*)(ws);                  // 19456 B
    int*           histb  = (int*)(ws + 19456);            // K*NB1*4 = 38912 B
    unsigned char* pred   = (unsigned char*)(ws + 58368);  // 131072 B
    float*         spart  = (float*)(ws + 189440);         // K*NC*NCHUNK*4 = 77824 B
    float*         pos0   = (float*)(ws + 267264);         // 19456 B

    hipLaunchKernelGGL(k1_argmax, dim3(NB1),        dim3(256), 0, stream, res, out, pred, histb, sums);
    hipLaunchKernelGGL(k2_pool,   dim3(BS * NC),    dim3(256), 0, stream, fea, pred, sums);
    hipLaunchKernelGGL(k4_lse,    dim3(NC, NCHUNK), dim3(256), 0, stream, queues, sums, spart, pos0);
    hipLaunchKernelGGL(k5_final,  dim3(1),          dim3(256), 0, stream, spart, pos0, histb, loss);
}

// Round 11
// 60.957 us; speedup vs baseline: 3.4425x; 3.4425x over previous
//
#include <hip/hip_runtime.h>

#define HW 16384      // 128*128
#define BS 8
#define NC 256        // feature channels
#define K  19         // classes
#define Q  2975
#define INV_T 5.0f    // 1/0.2
#define NCHUNK 4
#define QC 744        // 4*744 = 2976 >= 2975
#define NB1 512       // k1 grid: NB1*256 == BS*HW == 131072 exactly (1 pixel/thread)

// ---------------- K1: argmax + copy res->out + per-block histogram ----------------
// scalar float per thread, 512 blocks; block0 zeroes sums; nontemporal out stores
__global__ void __launch_bounds__(256) k1_argmax(const float* __restrict__ res,
                                                 float* __restrict__ out,
                                                 unsigned char* __restrict__ pred,
                                                 int* __restrict__ histb,
                                                 float* __restrict__ sums) {
    __shared__ int hist[K];
    int t = threadIdx.x;
    if (t < K) hist[t] = 0;
    __syncthreads();
    int gp = blockIdx.x * 256 + t;          // 0 .. BS*HW-1, exact cover
    int b  = gp >> 14;
    int p  = gp & (HW - 1);
    const float* rb = res + (size_t)b * K * HW + p;
    float*       ob = out + (size_t)b * K * HW + p;
    float best = rb[0];
    int   bk   = 0;
    __builtin_nontemporal_store(best, &ob[0]);
    #pragma unroll
    for (int k = 1; k < K; ++k) {
        float v = rb[(size_t)k * HW];
        __builtin_nontemporal_store(v, &ob[(size_t)k * HW]);
        if (v > best) { best = v; bk = k; }   // strict > keeps first index
    }
    pred[gp] = (unsigned char)bk;
    atomicAdd(&hist[bk], 1);
    if (blockIdx.x == 0) {                    // zero sums for k2
        for (int i = t; i < K * NC; i += 256) sums[i] = 0.f;
    }
    __syncthreads();
    if (t < K) histb[t * NB1 + blockIdx.x] = hist[t];   // k-major, no global atomics
}

// ---------------- K2: per-class pooling: sums[k][c] = sum of fea over pred==k ----------------
// one block per (b,c) row; per-thread LDS column accumulators.
// Element j of thread t uses column (t + 64j) & 255: the 4 addresses per iteration are
// provably distinct (their differences are never multiples of 256), so reads can be
// hoisted before writes -> 4-way ILP instead of a serialized RMW chain, and correctness
// holds even when all 4 pixels share a class. Final reduce sums all 256 columns anyway.
__global__ void __launch_bounds__(256) k2_pool(const float* __restrict__ fea,
                                               const unsigned char* __restrict__ pred,
                                               float* __restrict__ sums) {
    __shared__ float acc[K * 256];
    int t = threadIdx.x, lane = t & 63, w = t >> 6;
    int b = blockIdx.x >> 8;
    int c = blockIdx.x & 255;
    #pragma unroll
    for (int k = 0; k < K; ++k) acc[k * 256 + t] = 0.f;
    __syncthreads();
    const float4* f4 = (const float4*)(fea + (size_t)(b * NC + c) * HW);
    const uchar4* p4 = (const uchar4*)(pred + (size_t)b * HW);
    int c0 = t, c1 = (t + 64) & 255, c2 = (t + 128) & 255, c3 = (t + 192) & 255;
    #pragma unroll 2
    for (int i = t; i < HW / 4; i += 256) {
        float4 v  = f4[i];
        uchar4 kk = p4[i];
        int i0 = kk.x * 256 + c0, i1 = kk.y * 256 + c1;
        int i2 = kk.z * 256 + c2, i3 = kk.w * 256 + c3;
        float a0 = acc[i0], a1 = acc[i1], a2 = acc[i2], a3 = acc[i3];  // 4 independent reads
        acc[i0] = a0 + v.x;                                            // then 4 writes
        acc[i1] = a1 + v.y;
        acc[i2] = a2 + v.z;
        acc[i3] = a3 + v.w;
    }
    __syncthreads();
    // wave w reduces classes k = w, w+4, ... : 4 LDS reads + shuffle tree + 1 atomic
    for (int k = w; k < K; k += 4) {
        float v = acc[k * 256 + lane]       + acc[k * 256 + lane + 64]
                + acc[k * 256 + lane + 128] + acc[k * 256 + lane + 192];
        #pragma unroll
        for (int off = 32; off > 0; off >>= 1) v += __shfl_xor(v, off, 64);
        if (lane == 0) atomicAdd(&sums[k * NC + c], v);
    }
}

// ---------------- K4: inline norms + partial sum-of-exp over a q-chunk (fixed max = 0) ----
// grid (NC, NCHUNK); block 256.
// keys = sums / max(||sums||, 1e-12)  (cnt term in the reference eps can only matter if
// 1e-12 <= ||sums|| < cnt*1e-12 <= 1.3e-7 — impossible: present classes have O(1) norms,
// absent classes are exactly 0 and give key = 0 either way)
__global__ void __launch_bounds__(256, 4) k4_lse(const float* __restrict__ queues,
                                                 const float* __restrict__ sums,
                                                 float* __restrict__ spart,
                                                 float* __restrict__ pos0) {
    int t = threadIdx.x;
    int c = blockIdx.x;
    int chunk = blockIdx.y;
    int lane = t & 63, wv = t >> 6;

    // --- phase A: per-class INV_T/||sums|| (wave wv handles k = wv, wv+4, ...) ---
    __shared__ float sc_sh[K];
    for (int k = wv; k < K; k += 4) {
        float ss = 0.f;
        #pragma unroll
        for (int j = 0; j < 4; ++j) {
            float v = sums[k * NC + j * 64 + lane];
            ss += v * v;
        }
        #pragma unroll
        for (int off = 32; off > 0; off >>= 1) ss += __shfl_xor(ss, off, 64);
        if (lane == 0) sc_sh[k] = INV_T / fmaxf(sqrtf(ss), 1e-12f);
    }
    __syncthreads();

    float key[K], s[K];
    #pragma unroll
    for (int k = 0; k < K; ++k) {
        key[k] = sums[k * NC + c] * sc_sh[k];   // uniform addr -> broadcast load
        s[k] = 0.f;
    }
    if (chunk == 0 && t < K)
        pos0[t * NC + c] = sums[t * NC + c] * sc_sh[t] * queues[(size_t)(t * NC + c) * Q];

    int q0 = chunk * QC;
    int qhi = min(Q, q0 + QC);
    for (int q = q0 + t; q < qhi; q += 256) {
        float qv[K];
        float qs = 0.f;
        #pragma unroll
        for (int k = 0; k < K; ++k) {
            qv[k] = queues[(size_t)(k * NC + c) * Q + q];
            qs += qv[k];
        }
        #pragma unroll
        for (int k = 0; k < K; ++k) {
            float a  = key[k] * qv[k];                // l_pos/T
            float bn = fmaf(key[k], qs, -a);          // l_neg/T
            s[k] += __expf(a) + __expf(bn);
        }
    }

    // reduce s[k] across the block: per-wave shuffles, then cross-wave via LDS
    __shared__ float sw[K][4];
    #pragma unroll
    for (int k = 0; k < K; ++k) {
        float sk = s[k];
        #pragma unroll
        for (int off = 32; off > 0; off >>= 1) sk += __shfl_xor(sk, off, 64);
        if (lane == 0) sw[k][wv] = sk;
    }
    __syncthreads();
    if (t < K)
        spart[((size_t)t * NC + c) * NCHUNK + chunk] = sw[t][0] + sw[t][1] + sw[t][2] + sw[t][3];
}

// ---------------- K5: counts from histb + merge chunks + loss ----------------
__global__ void k5_final(const float* __restrict__ spart, const float* __restrict__ pos0,
                         const int* __restrict__ histb, float* __restrict__ loss) {
    __shared__ float cnt_sh[K];
    int t = threadIdx.x, lane = t & 63, w = t >> 6;
    for (int k = w; k < K; k += 4) {
        float cf = 0.f;
        #pragma unroll
        for (int j = 0; j < NB1 / 64; ++j)
            cf += (float)histb[k * NB1 + j * 64 + lane];
        #pragma unroll
        for (int off = 32; off > 0; off >>= 1) cf += __shfl_xor(cf, off, 64);
        if (lane == 0) cnt_sh[k] = cf;
    }
    __syncthreads();
    float acc = 0.f;   // thread t plays channel c = t
    #pragma unroll
    for (int k = 0; k < K; ++k) {
        float4 sp = ((const float4*)spart)[k * NC + t];
        float lse = logf(sp.x + sp.y + sp.z + sp.w);
        if (cnt_sh[k] > 0.5f) acc += lse - pos0[k * NC + t];
    }
    __shared__ float red[256];
    red[t] = acc;
    __syncthreads();
    for (int s = 128; s > 0; s >>= 1) {
        if (t < s) red[t] += red[t + s];
        __syncthreads();
    }
    if (t == 0) *loss = red[0] * (1.0f / 256.0f);
}

extern "C" void kernel_launch(void* const* d_in, const int* in_sizes, int n_in,
                              void* d_out, int out_size, void* d_ws, size_t ws_size,
                              hipStream_t stream) {
    const float* fea    = (const float*)d_in[0];   // [8,256,128,128]
    const float* res    = (const float*)d_in[1];   // [8,19,128,128]
    const float* queues = (const float*)d_in[2];   // [19,256,2975]

    float* out  = (float*)d_out;                   // res copy, then loss scalar
    float* loss = out + (size_t)BS * K * HW;       // element 2490368

    char* ws = (char*)d_ws;
    float*         sums   = (float*)(ws);                  // 19456 B
    int*           histb  = (int*)(ws + 19456);            // K*NB1*4 = 38912 B
    unsigned char* pred   = (unsigned char*)(ws + 58368);  // 131072 B
    float*         spart  = (float*)(ws + 189440);         // K*NC*NCHUNK*4 = 77824 B
    float*         pos0   = (float*)(ws + 267264);         // 19456 B

    hipLaunchKernelGGL(k1_argmax, dim3(NB1),        dim3(256), 0, stream, res, out, pred, histb, sums);
    hipLaunchKernelGGL(k2_pool,   dim3(BS * NC),    dim3(256), 0, stream, fea, pred, sums);
    hipLaunchKernelGGL(k4_lse,    dim3(NC, NCHUNK), dim3(256), 0, stream, queues, sums, spart, pos0);
    hipLaunchKernelGGL(k5_final,  dim3(1),          dim3(256), 0, stream, spart, pos0, histb, loss);
}

// Round 12
// 50.787 us; speedup vs baseline: 4.1319x; 1.2003x over previous
//
#include <hip/hip_runtime.h>

#define HW 16384      // 128*128
#define BS 8
#define NC 256        // feature channels
#define K  19         // classes
#define Q  2975
#define INV_T 5.0f    // 1/0.2
#define NB1 512       // k1 grid: NB1*256 == BS*HW == 131072 exactly (1 pixel/thread)

// ---------------- K1: argmax + copy res->out + per-block histogram ----------------
// scalar float per thread, 512 blocks; block0 zeroes sums + loss; nontemporal out stores
__global__ void __launch_bounds__(256) k1_argmax(const float* __restrict__ res,
                                                 float* __restrict__ out,
                                                 unsigned char* __restrict__ pred,
                                                 int* __restrict__ histb,
                                                 float* __restrict__ sums,
                                                 float* __restrict__ loss) {
    __shared__ int hist[K];
    int t = threadIdx.x;
    if (t < K) hist[t] = 0;
    __syncthreads();
    int gp = blockIdx.x * 256 + t;          // 0 .. BS*HW-1, exact cover
    int b  = gp >> 14;
    int p  = gp & (HW - 1);
    const float* rb = res + (size_t)b * K * HW + p;
    float*       ob = out + (size_t)b * K * HW + p;
    float best = rb[0];
    int   bk   = 0;
    __builtin_nontemporal_store(best, &ob[0]);
    #pragma unroll
    for (int k = 1; k < K; ++k) {
        float v = rb[(size_t)k * HW];
        __builtin_nontemporal_store(v, &ob[(size_t)k * HW]);
        if (v > best) { best = v; bk = k; }   // strict > keeps first index
    }
    pred[gp] = (unsigned char)bk;
    atomicAdd(&hist[bk], 1);
    if (blockIdx.x == 0) {                    // zero sums for k2, loss for k4
        for (int i = t; i < K * NC; i += 256) sums[i] = 0.f;
        if (t == 0) *loss = 0.f;
    }
    __syncthreads();
    if (t < K) histb[t * NB1 + blockIdx.x] = hist[t];   // k-major, no global atomics
}

// ---------------- K2: per-class pooling: sums[k][c] = sum of fea over pred==k ----------------
// one block per (b,c) row; per-thread LDS column accumulators.
// Element j of thread t uses column (t + 64j) & 255: the 4 addresses per iteration are
// provably distinct (differences never multiples of 256), so 4 reads can be hoisted
// before 4 writes -> ILP instead of a serialized RMW chain; correctness holds even when
// all 4 pixels share a class. Final reduce sums all 256 columns anyway.
__global__ void __launch_bounds__(256) k2_pool(const float* __restrict__ fea,
                                               const unsigned char* __restrict__ pred,
                                               float* __restrict__ sums) {
    __shared__ float acc[K * 256];
    int t = threadIdx.x, lane = t & 63, w = t >> 6;
    int b = blockIdx.x >> 8;
    int c = blockIdx.x & 255;
    #pragma unroll
    for (int k = 0; k < K; ++k) acc[k * 256 + t] = 0.f;
    __syncthreads();
    const float4* f4 = (const float4*)(fea + (size_t)(b * NC + c) * HW);
    const uchar4* p4 = (const uchar4*)(pred + (size_t)b * HW);
    int c0 = t, c1 = (t + 64) & 255, c2 = (t + 128) & 255, c3 = (t + 192) & 255;
    #pragma unroll 4
    for (int i = t; i < HW / 4; i += 256) {
        float4 v  = f4[i];
        uchar4 kk = p4[i];
        int i0 = kk.x * 256 + c0, i1 = kk.y * 256 + c1;
        int i2 = kk.z * 256 + c2, i3 = kk.w * 256 + c3;
        float a0 = acc[i0], a1 = acc[i1], a2 = acc[i2], a3 = acc[i3];  // 4 independent reads
        acc[i0] = a0 + v.x;                                            // then 4 writes
        acc[i1] = a1 + v.y;
        acc[i2] = a2 + v.z;
        acc[i3] = a3 + v.w;
    }
    __syncthreads();
    // wave w reduces classes k = w, w+4, ... : 4 LDS reads + shuffle tree + 1 atomic
    for (int k = w; k < K; k += 4) {
        float v = acc[k * 256 + lane]       + acc[k * 256 + lane + 64]
                + acc[k * 256 + lane + 128] + acc[k * 256 + lane + 192];
        #pragma unroll
        for (int off = 32; off > 0; off >>= 1) v += __shfl_xor(v, off, 64);
        if (lane == 0) atomicAdd(&sums[k * NC + c], v);
    }
}

// ---------------- K4: norms + counts + full-Q sum-of-exp + loss contribution ----------
// grid (NC); block 1024 (16 waves). Each block owns channel c over ALL of Q, so the
// chunk-merge kernel disappears: one atomicAdd per block into loss (zeroed by k1).
// keys = sums / max(||sums||, 1e-12)  (cnt term of the reference eps can only matter if
// 1e-12 <= ||sums|| < cnt*1e-12 <= 1.3e-7 — impossible; absent classes give key = 0)
__global__ void __launch_bounds__(1024, 4) k4_lse(const float* __restrict__ queues,
                                                  const float* __restrict__ sums,
                                                  const int* __restrict__ histb,
                                                  float* __restrict__ loss) {
    int t = threadIdx.x;
    int c = blockIdx.x;
    int lane = t & 63, wv = t >> 6;        // 16 waves

    // --- phase A: per-class INV_T/||sums|| and counts (wave wv: k = wv, wv+16) ---
    __shared__ float sc_sh[K], cnt_sh[K];
    for (int k = wv; k < K; k += 16) {
        float ss = 0.f, cf = 0.f;
        #pragma unroll
        for (int j = 0; j < 4; ++j) {
            float v = sums[k * NC + j * 64 + lane];
            ss += v * v;
        }
        #pragma unroll
        for (int j = 0; j < NB1 / 64; ++j)
            cf += (float)histb[k * NB1 + j * 64 + lane];
        #pragma unroll
        for (int off = 32; off > 0; off >>= 1) {
            ss += __shfl_xor(ss, off, 64);
            cf += __shfl_xor(cf, off, 64);
        }
        if (lane == 0) {
            sc_sh[k]  = INV_T / fmaxf(sqrtf(ss), 1e-12f);
            cnt_sh[k] = cf;
        }
    }
    __syncthreads();

    float key[K], s[K];
    #pragma unroll
    for (int k = 0; k < K; ++k) {
        key[k] = sums[k * NC + c] * sc_sh[k];   // uniform addr -> broadcast load
        s[k] = 0.f;
    }

    for (int q = t; q < Q; q += 1024) {
        float qv[K];
        float qs = 0.f;
        #pragma unroll
        for (int k = 0; k < K; ++k) {
            qv[k] = queues[(size_t)(k * NC + c) * Q + q];
            qs += qv[k];
        }
        #pragma unroll
        for (int k = 0; k < K; ++k) {
            float a  = key[k] * qv[k];                // l_pos/T
            float bn = fmaf(key[k], qs, -a);          // l_neg/T
            s[k] += __expf(a) + __expf(bn);
        }
    }

    // reduce s[k]: per-wave shuffles, then cross-wave via LDS
    __shared__ float sw[K][16];
    #pragma unroll
    for (int k = 0; k < K; ++k) {
        float sk = s[k];
        #pragma unroll
        for (int off = 32; off > 0; off >>= 1) sk += __shfl_xor(sk, off, 64);
        if (lane == 0) sw[k][wv] = sk;
    }
    __syncthreads();
    __shared__ float red[32];
    if (t < K) {
        float S = 0.f;
        #pragma unroll
        for (int w2 = 0; w2 < 16; ++w2) S += sw[t][w2];
        float lse   = logf(S);
        float key_t = sums[t * NC + c] * sc_sh[t];                    // recompute (no runtime reg-index)
        float pos0  = key_t * queues[(size_t)(t * NC + c) * Q];       // logit_0
        red[t] = (cnt_sh[t] > 0.5f) ? (lse - pos0) : 0.f;
    }
    __syncthreads();
    if (t == 0) {
        float acc = 0.f;
        #pragma unroll
        for (int k = 0; k < K; ++k) acc += red[k];
        atomicAdd(loss, acc * (1.0f / 256.0f));
    }
}

extern "C" void kernel_launch(void* const* d_in, const int* in_sizes, int n_in,
                              void* d_out, int out_size, void* d_ws, size_t ws_size,
                              hipStream_t stream) {
    const float* fea    = (const float*)d_in[0];   // [8,256,128,128]
    const float* res    = (const float*)d_in[1];   // [8,19,128,128]
    const float* queues = (const float*)d_in[2];   // [19,256,2975]

    float* out  = (float*)d_out;                   // res copy, then loss scalar
    float* loss = out + (size_t)BS * K * HW;       // element 2490368

    char* ws = (char*)d_ws;
    float*         sums  = (float*)(ws);                  // 19456 B
    int*           histb = (int*)(ws + 19456);            // K*NB1*4 = 38912 B
    unsigned char* pred  = (unsigned char*)(ws + 58368);  // 131072 B

    hipLaunchKernelGGL(k1_argmax, dim3(NB1),     dim3(256),  0, stream, res, out, pred, histb, sums, loss);
    hipLaunchKernelGGL(k2_pool,   dim3(BS * NC), dim3(256),  0, stream, fea, pred, sums);
    hipLaunchKernelGGL(k4_lse,    dim3(NC),      dim3(1024), 0, stream, queues, sums, histb, loss);
}